// Round 2
// baseline (202.502 us; speedup 1.0000x reference)
//
#include <hip/hip_runtime.h>
#include <math.h>

#define NN 50000
#define NE 800000
#define D  128
#define SCAN_CHUNK 1024
#define NSCAN ((NN + SCAN_CHUNK - 1) / SCAN_CHUNK)   // 49
#define PG_BLOCKS 782                                 // ceil((NE/4)/256)

typedef __attribute__((ext_vector_type(8))) short bf16x8;
typedef __attribute__((ext_vector_type(4))) float f32x4;

__device__ __forceinline__ unsigned short f32_to_bf16(float f) {
    unsigned u = __float_as_uint(f);
    u = u + 0x7FFFu + ((u >> 16) & 1u);   // RNE
    return (unsigned short)(u >> 16);
}

// fast tanh: 1 - 2*rcp(e^{2x}+1). Exact at saturation (e->inf: rcp=0 -> 1;
// e->0 -> -1). ~5 VALU vs ~18 for ocml tanhf. |err| ~ 1e-6, tol is 1.6e-2.
__device__ __forceinline__ float fast_tanh(float x) {
    float e = __expf(2.0f * x);
    return fmaf(-2.0f, __builtin_amdgcn_rcpf(e + 1.0f), 1.0f);
}

// ---- K1: degree atomics + per-edge rank; W bf16-frag pre-pack (block 0);
//      zero sentinel z-row NN (block 1); zero out-tail. --------------------
__global__ __launch_bounds__(256) void k_count(
        const float* __restrict__ Wg, const int* __restrict__ ei,
        int* __restrict__ deg, unsigned short* __restrict__ rank,
        unsigned short* __restrict__ wpk, unsigned short* __restrict__ zb,
        int* __restrict__ outtail, int tailN) {
    int tid = threadIdx.x;
    int g = blockIdx.x * 256 + tid;

    if (g < NE / 4) {
        int4 d4 = ((const int4*)(ei + NE))[g];
        ushort4 r;
        r.x = (unsigned short)atomicAdd(&deg[d4.x], 1);
        r.y = (unsigned short)atomicAdd(&deg[d4.y], 1);
        r.z = (unsigned short)atomicAdd(&deg[d4.z], 1);
        r.w = (unsigned short)atomicAdd(&deg[d4.w], 1);
        ((ushort4*)rank)[g] = r;
    }
    for (int i = g; i < tailN; i += PG_BLOCKS * 256) outtail[i] = 0;

    if (blockIdx.x == 0) {
        // output-linear: coalesced wpk stores, scattered (L2-cached) Wg reads.
        // frag = nt*256 + kt*64 + quad*16 + lo, elem j = k&7  (verified layout)
#pragma unroll 8
        for (int i = 0; i < 64; i++) {
            int o = i * 256 + tid;
            int j = o & 7, frag = o >> 3;
            int lo = frag & 15, quad = (frag >> 4) & 3;
            int kt = (frag >> 6) & 3, nt = frag >> 8;
            int k = kt * 32 + quad * 8 + j, n = nt * 16 + lo;
            wpk[o] = f32_to_bf16(Wg[k * 128 + n]);
        }
    }
    if (blockIdx.x == 1 && tid < 64)
        ((unsigned*)(zb + (size_t)NN * D))[tid] = 0u;   // sentinel row = 0
}

// ---- K2: fused scan: shfl-based wave scan (2 barriers, was 16) ------------
__global__ __launch_bounds__(256) void k_scan(const int* __restrict__ deg,
                                              int* __restrict__ partial,
                                              int* __restrict__ flag,
                                              int* __restrict__ rowoff,
                                              float* __restrict__ dinv) {
    __shared__ int wsum[4];
    int t = threadIdx.x;
    int bid = blockIdx.x;
    int lane = t & 63, wv = t >> 6;
    int base = bid * SCAN_CHUNK + t * 4;
    int d[4]; int s = 0;
#pragma unroll
    for (int j = 0; j < 4; j++) {
        int i = base + j;
        d[j] = 0;
        if (i < NN) {
            d[j] = deg[i];
            s += d[j];
            dinv[i] = rsqrtf((float)d[j] + 1.0f);   // +1 self loop
        }
    }
    // inclusive wave scan of s
    int v = s;
#pragma unroll
    for (int off = 1; off < 64; off <<= 1) {
        int u = __shfl_up(v, off, 64);
        if (lane >= off) v += u;
    }
    if (lane == 63) wsum[wv] = v;
    __syncthreads();
    int add = 0;
#pragma unroll
    for (int k = 0; k < 4; k++) if (k < wv) add += wsum[k];
    int inc = v + add;                  // inclusive over block

    if (t == 255) {                     // holds the block total
        atomicExch(&partial[bid], inc);
        __threadfence();
        atomicAdd(flag, 1);
        while (atomicAdd(flag, 0) < NSCAN) {}   // 49 blocks co-resident: safe
    }
    __syncthreads();

    int pv = (lane < NSCAN && lane < bid) ? atomicAdd(&partial[lane], 0) : 0;
#pragma unroll
    for (int off = 32; off > 0; off >>= 1) pv += __shfl_xor(pv, off, 64);

    int ex = inc - s + pv;              // exclusive prefix for this thread
#pragma unroll
    for (int j = 0; j < 4; j++) {
        int i = base + j;
        if (i < NN) {
            rowoff[i] = ex;
            ex += d[j];
            if (i == NN - 1) rowoff[NN] = ex;   // sentinel = NE
        }
    }
}

// ---- K3: z' = dinv (hW) in bf16 + CSR fill, fused. No LDS, no barrier. ----
__global__ __launch_bounds__(256) void k_gemm_fill(
        const float* __restrict__ h, const uint4* __restrict__ wpk4,
        const int* __restrict__ ei, const unsigned short* __restrict__ rank,
        const int* __restrict__ rowoff, const float* __restrict__ dinv,
        unsigned short* __restrict__ zb, int* __restrict__ csr) {
    int tid = threadIdx.x;
    int g = blockIdx.x * 256 + tid;

    // CSR fill first: issue the random rowoff gathers as early as possible
    if (g < NE / 4) {
        int4 s4 = ((const int4*)ei)[g];
        int4 d4 = ((const int4*)(ei + NE))[g];
        ushort4 r4 = ((const ushort4*)rank)[g];
        csr[rowoff[d4.x] + r4.x] = s4.x;
        csr[rowoff[d4.y] + r4.y] = s4.y;
        csr[rowoff[d4.z] + r4.z] = s4.z;
        csr[rowoff[d4.w] + r4.w] = s4.w;
    }

    int w = tid >> 6, lane = tid & 63;
    int quad = lane >> 4, lo = lane & 15;
    int rowBase = blockIdx.x * 64 + w * 16;
    int rowA = rowBase + lo; if (rowA > NN - 1) rowA = NN - 1;
    const float4* h4 = (const float4*)h;

    bf16x8 af[4];
#pragma unroll
    for (int kt = 0; kt < 4; kt++) {
        float4 u = h4[(size_t)rowA * 32 + kt * 8 + quad * 2];
        float4 v = h4[(size_t)rowA * 32 + kt * 8 + quad * 2 + 1];
        bf16x8 a;
        a[0] = (short)f32_to_bf16(u.x); a[1] = (short)f32_to_bf16(u.y);
        a[2] = (short)f32_to_bf16(u.z); a[3] = (short)f32_to_bf16(u.w);
        a[4] = (short)f32_to_bf16(v.x); a[5] = (short)f32_to_bf16(v.y);
        a[6] = (short)f32_to_bf16(v.z); a[7] = (short)f32_to_bf16(v.w);
        af[kt] = a;
    }

    f32x4 acc[8];
#pragma unroll
    for (int nt = 0; nt < 8; nt++) acc[nt] = (f32x4){0.f, 0.f, 0.f, 0.f};

#pragma unroll
    for (int kt = 0; kt < 4; kt++) {
#pragma unroll
        for (int nt = 0; nt < 8; nt++) {
            uint4 tb = wpk4[nt * 256 + kt * 64 + lane];   // coalesced, L1-hit
            bf16x8 bfv = __builtin_bit_cast(bf16x8, tb);
            acc[nt] = __builtin_amdgcn_mfma_f32_16x16x32_bf16(af[kt], bfv, acc[nt], 0, 0, 0);
        }
    }

#pragma unroll
    for (int reg = 0; reg < 4; reg++) {
        int row = rowBase + quad * 4 + reg;
        if (row < NN) {
            float dn = dinv[row];
#pragma unroll
            for (int nt = 0; nt < 8; nt++)
                zb[(size_t)row * D + nt * 16 + lo] = f32_to_bf16(acc[nt][reg] * dn);
        }
    }
}

// ---- K4: weightless gather + LN + tanh. Coalesced csr vector load (64
// idx/load) + v_readlane broadcast (1 VALU/edge, no DS, no s_load chain).
// One pad-select per 64-edge chunk; 16 gathers in flight; sentinel row NN.
__global__ __launch_bounds__(256) void k_gather_ln(
        const int* __restrict__ rowoff, const int* __restrict__ csr,
        const float* __restrict__ dinv, const unsigned* __restrict__ zbu,
        const float* __restrict__ bias, const float* __restrict__ gamma,
        const float* __restrict__ beta, float* __restrict__ out) {
    int tid = threadIdx.x;
    int w = tid >> 6, lane = tid & 63;
    int rowBase = blockIdx.x * 16 + w * 4;

    // issue all 4 rows' metadata + self-row + first-chunk loads up front
    int cs[4], ce[4]; float dn[4]; unsigned selfz[4]; int v0[4];
#pragma unroll
    for (int r = 0; r < 4; r++) {
        int row = rowBase + r;
        cs[r] = __builtin_amdgcn_readfirstlane(rowoff[row]);
        ce[r] = __builtin_amdgcn_readfirstlane(rowoff[row + 1]);
        dn[r] = dinv[row];
        selfz[r] = zbu[(size_t)row * 64 + lane];
    }
#pragma unroll
    for (int r = 0; r < 4; r++) {
        int m0 = ce[r] - cs[r]; if (m0 > 64) m0 = 64;
        int t0 = csr[cs[r] + lane];          // csr padded +64: always in-bounds
        v0[r] = (lane < m0) ? t0 : NN;       // pad -> zero sentinel row
    }

    float2 x[4];
#pragma unroll
    for (int r = 0; r < 4; r++) {
        float ax = __uint_as_float(selfz[r] << 16);
        float ay = __uint_as_float(selfz[r] & 0xFFFF0000u);
        int c = cs[r];
        int v = v0[r];
        while (true) {
            int m = ce[r] - c; if (m > 64) m = 64;
            int nb = (m + 15) >> 4;          // uniform batch count
            for (int jb = 0; jb < nb; ++jb) {
                int j = jb << 4;
                unsigned p[16];
#pragma unroll
                for (int q = 0; q < 16; q++) {
                    int sq = __builtin_amdgcn_readlane(v, j + q);
                    p[q] = zbu[(size_t)sq * 64 + lane];
                }
#pragma unroll
                for (int q = 0; q < 16; q++) {
                    ax += __uint_as_float(p[q] << 16);
                    ay += __uint_as_float(p[q] & 0xFFFF0000u);
                }
            }
            c += 64;
            if (c >= ce[r]) break;
            int m2 = ce[r] - c; if (m2 > 64) m2 = 64;
            int t2 = csr[c + lane];
            v = (lane < m2) ? t2 : NN;
        }
        x[r].x = ax * dn[r];
        x[r].y = ay * dn[r];
    }

    float2 bi = ((const float2*)bias)[lane];
    float2 ga = ((const float2*)gamma)[lane];
    float2 be = ((const float2*)beta)[lane];
#pragma unroll
    for (int r = 0; r < 4; r++) {
        int row = rowBase + r;
        float y0 = x[r].x + bi.x;
        float y1 = x[r].y + bi.y;
        float s = y0 + y1;
#pragma unroll
        for (int off = 32; off > 0; off >>= 1) s += __shfl_xor(s, off, 64);
        float m = s * (1.0f / 128.0f);
        float v0f = y0 - m, v1f = y1 - m;
        float vs = v0f * v0f + v1f * v1f;
#pragma unroll
        for (int off = 32; off > 0; off >>= 1) vs += __shfl_xor(vs, off, 64);
        float rstd = rsqrtf(vs * (1.0f / 128.0f) + 1e-5f);
        float2 o;
        o.x = fast_tanh(v0f * rstd * ga.x + be.x);
        o.y = fast_tanh(v1f * rstd * ga.y + be.y);
        *(float2*)&out[(size_t)row * D + lane * 2] = o;
    }
}

extern "C" void kernel_launch(void* const* d_in, const int* in_sizes, int n_in,
                              void* d_out, int out_size, void* d_ws, size_t ws_size,
                              hipStream_t stream) {
    // inputs: t, h, edge_index, batch_size, W, b, gamma, beta
    const float* h     = (const float*)d_in[1];
    const int*   ei    = (const int*)  d_in[2];
    const float* Wg    = (const float*)d_in[4];
    const float* b     = (const float*)d_in[5];
    const float* gamma = (const float*)d_in[6];
    const float* beta  = (const float*)d_in[7];
    float* out = (float*)d_out;

    // workspace layout (~18.8 MB). csr has +64-int pad (branchless chunk loads).
    char* wsb = (char*)d_ws;
    unsigned short* wpk    = (unsigned short*)(wsb);            // 32768 B
    int*            deg    = (int*)(wsb + 32768);               // NN ints
    int*            flag   = (int*)(wsb + 232768);              // 1 int (adjacent to deg)
    int*            partial= (int*)(wsb + 232832);              // 64 ints
    unsigned short* rank   = (unsigned short*)(wsb + 233088);   // NE ushorts
    int*            rowoff = (int*)(wsb + 1833088);             // NN+1 ints
    float*          dinv   = (float*)(wsb + 2633152);           // NN floats
    int*            csr    = (int*)(wsb + 2833152);             // NE ints + 64 pad
    unsigned short* zb     = (unsigned short*)(wsb + 6033408);  // (NN+1)*128 ushorts

    int tailN = out_size - NN * D;                 // int-zeros tail of d_out
    int* outtail = (int*)(out + (size_t)NN * D);

    hipMemsetAsync(deg, 0, NN * sizeof(int) + sizeof(int), stream);   // deg + flag
    k_count    <<<PG_BLOCKS, 256, 0, stream>>>(Wg, ei, deg, rank, wpk, zb, outtail, tailN);
    k_scan     <<<NSCAN,     256, 0, stream>>>(deg, partial, flag, rowoff, dinv);
    k_gemm_fill<<<PG_BLOCKS, 256, 0, stream>>>(h, (const uint4*)wpk, ei, rank, rowoff, dinv, zb, csr);
    k_gather_ln<<<NN / 16,   256, 0, stream>>>(rowoff, csr, dinv, (const unsigned*)zb, b, gamma, beta, out);
}

// Round 3
// 192.497 us; speedup vs baseline: 1.0520x; 1.0520x over previous
//
#include <hip/hip_runtime.h>
#include <math.h>

#define NN 50000
#define NE 800000
#define D  128
#define SCAN_CHUNK 1024
#define NSCAN ((NN + SCAN_CHUNK - 1) / SCAN_CHUNK)   // 49
#define PG_BLOCKS 782                                 // ceil((NE/4)/256)

typedef __attribute__((ext_vector_type(8))) short bf16x8;
typedef __attribute__((ext_vector_type(4))) float f32x4;

__device__ __forceinline__ unsigned short f32_to_bf16(float f) {
    unsigned u = __float_as_uint(f);
    u = u + 0x7FFFu + ((u >> 16) & 1u);   // RNE
    return (unsigned short)(u >> 16);
}

// fast tanh: 1 - 2*rcp(e^{2x}+1). Exact at saturation. |err| ~1e-6.
__device__ __forceinline__ float fast_tanh(float x) {
    float e = __expf(2.0f * x);
    return fmaf(-2.0f, __builtin_amdgcn_rcpf(e + 1.0f), 1.0f);
}

// ---- K0 (replaces memset): zero deg+flag; pack W bf16 fragments (block 0);
//      zero zb sentinel row NN (block 1). Must precede K1's GEMM blocks. ----
__global__ __launch_bounds__(256) void k_init(
        const float* __restrict__ Wg, int* __restrict__ deg,
        unsigned short* __restrict__ wpk, unsigned short* __restrict__ zb) {
    int tid = threadIdx.x;
    int idx = blockIdx.x * 256 + tid;

    if (idx < 12500) ((int4*)deg)[idx] = (int4){0, 0, 0, 0};   // 50000 ints
    if (idx == 12500) deg[50000] = 0;                          // flag (adjacent)

    if (blockIdx.x == 0) {
        // output-linear: coalesced wpk stores, scattered (L2-resident) Wg reads
        // frag = nt*256 + kt*64 + quad*16 + lo, elem j = k&7 (verified layout)
#pragma unroll 8
        for (int i = 0; i < 64; i++) {
            int o = i * 256 + tid;
            int j = o & 7, frag = o >> 3;
            int lo = frag & 15, quad = (frag >> 4) & 3;
            int kt = (frag >> 6) & 3, nt = frag >> 8;
            int k = kt * 32 + quad * 8 + j, n = nt * 16 + lo;
            wpk[o] = f32_to_bf16(Wg[k * 128 + n]);
        }
    }
    if (blockIdx.x == 1 && tid < 64)
        ((unsigned*)(zb + (size_t)NN * D))[tid] = 0u;   // sentinel row = 0
}

// ---- K1: count-atomics blocks + GEMM blocks interleaved by parity.
// GEMM writes UNSCALED fp32 zf (no dinv dep) -> overlaps with atomics. ------
__global__ __launch_bounds__(256) void k_count_gemm(
        const float* __restrict__ h, const uint4* __restrict__ wpk4,
        const int* __restrict__ ei, int* __restrict__ deg,
        unsigned short* __restrict__ rank, float* __restrict__ zf,
        int* __restrict__ outtail, int tailN) {
    int tid = threadIdx.x;
    int bid = blockIdx.x;

    if (bid & 1) {
        // ---- count role: 782 blocks, 4 edges/thread + out-tail zero ----
        int g = (bid >> 1) * 256 + tid;
        if (g < NE / 4) {
            int4 d4 = ((const int4*)(ei + NE))[g];
            ushort4 r;
            r.x = (unsigned short)atomicAdd(&deg[d4.x], 1);
            r.y = (unsigned short)atomicAdd(&deg[d4.y], 1);
            r.z = (unsigned short)atomicAdd(&deg[d4.z], 1);
            r.w = (unsigned short)atomicAdd(&deg[d4.w], 1);
            ((ushort4*)rank)[g] = r;
        }
        for (int i = g; i < tailN; i += PG_BLOCKS * 256) outtail[i] = 0;
        return;
    }

    // ---- GEMM role: 782 blocks, 64 rows each, zf = hW (fp32) ----
    int gid = bid >> 1;
    int w = tid >> 6, lane = tid & 63;
    int quad = lane >> 4, lo = lane & 15;
    int rowBase = gid * 64 + w * 16;
    int rowA = rowBase + lo; if (rowA > NN - 1) rowA = NN - 1;
    const float4* h4 = (const float4*)h;

    bf16x8 af[4];
#pragma unroll
    for (int kt = 0; kt < 4; kt++) {
        float4 u = h4[(size_t)rowA * 32 + kt * 8 + quad * 2];
        float4 v = h4[(size_t)rowA * 32 + kt * 8 + quad * 2 + 1];
        bf16x8 a;
        a[0] = (short)f32_to_bf16(u.x); a[1] = (short)f32_to_bf16(u.y);
        a[2] = (short)f32_to_bf16(u.z); a[3] = (short)f32_to_bf16(u.w);
        a[4] = (short)f32_to_bf16(v.x); a[5] = (short)f32_to_bf16(v.y);
        a[6] = (short)f32_to_bf16(v.z); a[7] = (short)f32_to_bf16(v.w);
        af[kt] = a;
    }

    f32x4 acc[8];
#pragma unroll
    for (int nt = 0; nt < 8; nt++) acc[nt] = (f32x4){0.f, 0.f, 0.f, 0.f};

#pragma unroll
    for (int kt = 0; kt < 4; kt++) {
#pragma unroll
        for (int nt = 0; nt < 8; nt++) {
            uint4 tb = wpk4[nt * 256 + kt * 64 + lane];   // coalesced, L1-hit
            bf16x8 bfv = __builtin_bit_cast(bf16x8, tb);
            acc[nt] = __builtin_amdgcn_mfma_f32_16x16x32_bf16(af[kt], bfv, acc[nt], 0, 0, 0);
        }
    }

#pragma unroll
    for (int reg = 0; reg < 4; reg++) {
        int row = rowBase + quad * 4 + reg;
        if (row < NN) {
#pragma unroll
            for (int nt = 0; nt < 8; nt++)
                zf[(size_t)row * D + nt * 16 + lo] = acc[nt][reg];
        }
    }
}

// ---- K2: fused scan: shfl-based wave scan, device-atomic spin barrier -----
__global__ __launch_bounds__(256) void k_scan(const int* __restrict__ deg,
                                              int* __restrict__ partial,
                                              int* __restrict__ flag,
                                              int* __restrict__ rowoff,
                                              float* __restrict__ dinv) {
    __shared__ int wsum[4];
    int t = threadIdx.x;
    int bid = blockIdx.x;
    int lane = t & 63, wv = t >> 6;
    int base = bid * SCAN_CHUNK + t * 4;
    int d[4]; int s = 0;
#pragma unroll
    for (int j = 0; j < 4; j++) {
        int i = base + j;
        d[j] = 0;
        if (i < NN) {
            d[j] = deg[i];
            s += d[j];
            dinv[i] = rsqrtf((float)d[j] + 1.0f);   // +1 self loop
        }
    }
    int v = s;
#pragma unroll
    for (int off = 1; off < 64; off <<= 1) {
        int u = __shfl_up(v, off, 64);
        if (lane >= off) v += u;
    }
    if (lane == 63) wsum[wv] = v;
    __syncthreads();
    int add = 0;
#pragma unroll
    for (int k = 0; k < 4; k++) if (k < wv) add += wsum[k];
    int inc = v + add;                  // inclusive over block

    if (t == 255) {
        atomicExch(&partial[bid], inc);
        __threadfence();
        atomicAdd(flag, 1);
        while (atomicAdd(flag, 0) < NSCAN) {}   // 49 blocks co-resident: safe
    }
    __syncthreads();

    int pv = (lane < NSCAN && lane < bid) ? atomicAdd(&partial[lane], 0) : 0;
#pragma unroll
    for (int off = 32; off > 0; off >>= 1) pv += __shfl_xor(pv, off, 64);

    int ex = inc - s + pv;
#pragma unroll
    for (int j = 0; j < 4; j++) {
        int i = base + j;
        if (i < NN) {
            rowoff[i] = ex;
            ex += d[j];
            if (i == NN - 1) rowoff[NN] = ex;   // sentinel = NE
        }
    }
}

// ---- K3: CSR fill + zb = bf16(zf * dinv). Same rounding path as before
// (dinv applied to fp32 value, single RNE round) -> absmax identical. ------
__global__ __launch_bounds__(320) void k_fill_scale(
        const int* __restrict__ ei, const int* __restrict__ rowoff,
        const unsigned short* __restrict__ rank, int* __restrict__ csr,
        const float* __restrict__ zf, const float* __restrict__ dinv,
        unsigned short* __restrict__ zb) {
    int t = blockIdx.x * 320 + threadIdx.x;   // 625*320 = 200000 exactly

    // fill: scattered, latency-bound — issue first
    int4 s4 = ((const int4*)ei)[t];
    int4 d4 = ((const int4*)(ei + NE))[t];
    ushort4 r4 = ((const ushort4*)rank)[t];
    csr[rowoff[d4.x] + r4.x] = s4.x;
    csr[rowoff[d4.y] + r4.y] = s4.y;
    csr[rowoff[d4.z] + r4.z] = s4.z;
    csr[rowoff[d4.w] + r4.w] = s4.w;

    // scale: quarter-row per thread (32 floats), BW-bound, hides under fill
    int row = t >> 2, seg = t & 3;
    float dn = dinv[row];
    const float4* src = (const float4*)(zf + (size_t)row * D + seg * 32);
    uint4* dst = (uint4*)(zb + (size_t)row * D + seg * 32);
#pragma unroll
    for (int i = 0; i < 4; i++) {
        float4 a = src[i * 2], b = src[i * 2 + 1];
        uint4 o;
        o.x = (unsigned)f32_to_bf16(a.x * dn) | ((unsigned)f32_to_bf16(a.y * dn) << 16);
        o.y = (unsigned)f32_to_bf16(a.z * dn) | ((unsigned)f32_to_bf16(a.w * dn) << 16);
        o.z = (unsigned)f32_to_bf16(b.x * dn) | ((unsigned)f32_to_bf16(b.y * dn) << 16);
        o.w = (unsigned)f32_to_bf16(b.z * dn) | ((unsigned)f32_to_bf16(b.w * dn) << 16);
        dst[i] = o;
    }
}

// ---- K4: weightless gather + LN + tanh (unchanged from round 2) -----------
__global__ __launch_bounds__(256) void k_gather_ln(
        const int* __restrict__ rowoff, const int* __restrict__ csr,
        const float* __restrict__ dinv, const unsigned* __restrict__ zbu,
        const float* __restrict__ bias, const float* __restrict__ gamma,
        const float* __restrict__ beta, float* __restrict__ out) {
    int tid = threadIdx.x;
    int w = tid >> 6, lane = tid & 63;
    int rowBase = blockIdx.x * 16 + w * 4;

    int cs[4], ce[4]; float dn[4]; unsigned selfz[4]; int v0[4];
#pragma unroll
    for (int r = 0; r < 4; r++) {
        int row = rowBase + r;
        cs[r] = __builtin_amdgcn_readfirstlane(rowoff[row]);
        ce[r] = __builtin_amdgcn_readfirstlane(rowoff[row + 1]);
        dn[r] = dinv[row];
        selfz[r] = zbu[(size_t)row * 64 + lane];
    }
#pragma unroll
    for (int r = 0; r < 4; r++) {
        int m0 = ce[r] - cs[r]; if (m0 > 64) m0 = 64;
        int t0 = csr[cs[r] + lane];          // csr padded +64: in-bounds
        v0[r] = (lane < m0) ? t0 : NN;       // pad -> zero sentinel row
    }

    float2 x[4];
#pragma unroll
    for (int r = 0; r < 4; r++) {
        float ax = __uint_as_float(selfz[r] << 16);
        float ay = __uint_as_float(selfz[r] & 0xFFFF0000u);
        int c = cs[r];
        int v = v0[r];
        while (true) {
            int m = ce[r] - c; if (m > 64) m = 64;
            int nb = (m + 15) >> 4;
            for (int jb = 0; jb < nb; ++jb) {
                int j = jb << 4;
                unsigned p[16];
#pragma unroll
                for (int q = 0; q < 16; q++) {
                    int sq = __builtin_amdgcn_readlane(v, j + q);
                    p[q] = zbu[(size_t)sq * 64 + lane];
                }
#pragma unroll
                for (int q = 0; q < 16; q++) {
                    ax += __uint_as_float(p[q] << 16);
                    ay += __uint_as_float(p[q] & 0xFFFF0000u);
                }
            }
            c += 64;
            if (c >= ce[r]) break;
            int m2 = ce[r] - c; if (m2 > 64) m2 = 64;
            int t2 = csr[c + lane];
            v = (lane < m2) ? t2 : NN;
        }
        x[r].x = ax * dn[r];
        x[r].y = ay * dn[r];
    }

    float2 bi = ((const float2*)bias)[lane];
    float2 ga = ((const float2*)gamma)[lane];
    float2 be = ((const float2*)beta)[lane];
#pragma unroll
    for (int r = 0; r < 4; r++) {
        int row = rowBase + r;
        float y0 = x[r].x + bi.x;
        float y1 = x[r].y + bi.y;
        float s = y0 + y1;
#pragma unroll
        for (int off = 32; off > 0; off >>= 1) s += __shfl_xor(s, off, 64);
        float m = s * (1.0f / 128.0f);
        float v0f = y0 - m, v1f = y1 - m;
        float vs = v0f * v0f + v1f * v1f;
#pragma unroll
        for (int off = 32; off > 0; off >>= 1) vs += __shfl_xor(vs, off, 64);
        float rstd = rsqrtf(vs * (1.0f / 128.0f) + 1e-5f);
        float2 o;
        o.x = fast_tanh(v0f * rstd * ga.x + be.x);
        o.y = fast_tanh(v1f * rstd * ga.y + be.y);
        *(float2*)&out[(size_t)row * D + lane * 2] = o;
    }
}

extern "C" void kernel_launch(void* const* d_in, const int* in_sizes, int n_in,
                              void* d_out, int out_size, void* d_ws, size_t ws_size,
                              hipStream_t stream) {
    // inputs: t, h, edge_index, batch_size, W, b, gamma, beta
    const float* h     = (const float*)d_in[1];
    const int*   ei    = (const int*)  d_in[2];
    const float* Wg    = (const float*)d_in[4];
    const float* b     = (const float*)d_in[5];
    const float* gamma = (const float*)d_in[6];
    const float* beta  = (const float*)d_in[7];
    float* out = (float*)d_out;

    // workspace layout (~44.5 MB). csr has +64-int pad (branchless chunk loads).
    char* wsb = (char*)d_ws;
    unsigned short* wpk    = (unsigned short*)(wsb);            // 32768 B
    int*            deg    = (int*)(wsb + 32768);               // NN ints (+flag adjacent)
    int*            flag   = (int*)(wsb + 232768);              // 1 int
    int*            partial= (int*)(wsb + 232832);              // 64 ints
    unsigned short* rank   = (unsigned short*)(wsb + 233088);   // NE ushorts
    int*            rowoff = (int*)(wsb + 1833088);             // NN+1 ints
    float*          dinv   = (float*)(wsb + 2633152);           // NN floats
    int*            csr    = (int*)(wsb + 2833152);             // NE ints + 64 pad
    unsigned short* zb     = (unsigned short*)(wsb + 6033408);  // (NN+1)*128 ushorts
    float*          zf     = (float*)(wsb + 18833664);          // NN*128 floats

    int tailN = out_size - NN * D;                 // int-zeros tail of d_out
    int* outtail = (int*)(out + (size_t)NN * D);

    k_init      <<<64,            256, 0, stream>>>(Wg, deg, wpk, zb);
    k_count_gemm<<<PG_BLOCKS * 2, 256, 0, stream>>>(h, (const uint4*)wpk, ei, deg, rank, zf, outtail, tailN);
    k_scan      <<<NSCAN,         256, 0, stream>>>(deg, partial, flag, rowoff, dinv);
    k_fill_scale<<<625,           320, 0, stream>>>(ei, rowoff, rank, csr, zf, dinv, zb);
    k_gather_ln <<<NN / 16,       256, 0, stream>>>(rowoff, csr, dinv, (const unsigned*)zb, b, gamma, beta, out);
}